// Round 3
// baseline (398.723 us; speedup 1.0000x reference)
//
#include <hip/hip_runtime.h>

// Attention layer, MI355X. Internal bf16 MFMA compute (tolerance 7e-2 permits).
// Pipeline: cvt -> fused QKV GEMM -> RoPE -> V-transpose -> flash attn -> out GEMM.
// R3: flash v3 — NO K/V LDS staging (K/V are L2-resident; m169 lesson). Fragments
// read direct from global. LDS = 18KB P-buffer only, zero barriers, 512 blocks
// (2/CU, complementary q-tile sizes per CU via bh-half flip). exp2-domain softmax.

#define SQ 2048
#define DQ 2048
#define HQ 16
#define HDQ 128

typedef short bf16x8 __attribute__((ext_vector_type(8)));
typedef float f32x4 __attribute__((ext_vector_type(4)));

__device__ __forceinline__ short f2bf(float f) {
  union { float f; unsigned u; } v; v.f = f;
  unsigned r = (v.u + 0x7FFFu + ((v.u >> 16) & 1u)) >> 16;
  return (short)r;
}
__device__ __forceinline__ float bf2f(short b) {
  union { unsigned u; float f; } v; v.u = ((unsigned)(unsigned short)b) << 16;
  return v.f;
}
__device__ __forceinline__ void gload_lds16(const void* g, void* l) {
  __builtin_amdgcn_global_load_lds(
      (const __attribute__((address_space(1))) void*)g,
      (__attribute__((address_space(3))) void*)l, 16, 0, 0);
}

// ---------- fp32 -> bf16 (8 elems/thread) ----------
__global__ void cvt_kernel(const float* __restrict__ in, short* __restrict__ out, int nvec) {
  int i = blockIdx.x * blockDim.x + threadIdx.x;
  if (i >= nvec) return;
  const f32x4* p = (const f32x4*)in + (size_t)i * 2;
  f32x4 a = p[0], b = p[1];
  bf16x8 o;
  o[0] = f2bf(a[0]); o[1] = f2bf(a[1]); o[2] = f2bf(a[2]); o[3] = f2bf(a[3]);
  o[4] = f2bf(b[0]); o[5] = f2bf(b[1]); o[6] = f2bf(b[2]); o[7] = f2bf(b[3]);
  *((bf16x8*)out + i) = o;
}

// ---------- RoPE in-place on [BH, S, HD] bf16, pairs (2i,2i+1), + optional scale ----------
__global__ void rope_kernel(short* __restrict__ t, const float* __restrict__ cosT,
                            const float* __restrict__ sinT, float scale, int nvec) {
  int i = blockIdx.x * blockDim.x + threadIdx.x;
  if (i >= nvec) return;
  size_t off = (size_t)i * 8;
  int hd0 = (int)(off & 127);
  int s = (int)((off >> 7) & 2047);
  bf16x8 v = *((const bf16x8*)(t + off));
  f32x4 c  = *(const f32x4*)(cosT + (size_t)s * 64 + (hd0 >> 1));
  f32x4 sn = *(const f32x4*)(sinT + (size_t)s * 64 + (hd0 >> 1));
  bf16x8 o;
#pragma unroll
  for (int p = 0; p < 4; ++p) {
    float xr = bf2f(v[2 * p]), xi = bf2f(v[2 * p + 1]);
    o[2 * p]     = f2bf((xr * c[p] - xi * sn[p]) * scale);
    o[2 * p + 1] = f2bf((xr * sn[p] + xi * c[p]) * scale);
  }
  *((bf16x8*)(t + off)) = o;
}

// ---------- V [BH,S,HD] -> V^T [BH,HD,S] ----------
__global__ void vtrans_kernel(const short* __restrict__ vb, short* __restrict__ vtb) {
  __shared__ __align__(16) short tile[64][72];
  int bh = blockIdx.z, s0 = blockIdx.y * 64, d0 = blockIdx.x * 64;
  int tid = threadIdx.x;
#pragma unroll
  for (int it = 0; it < 2; ++it) {
    int vi = it * 256 + tid;
    int r = vi >> 3, c8 = (vi & 7) * 8;
    bf16x8 v = *(const bf16x8*)&vb[((size_t)bh * SQ + s0 + r) * HDQ + d0 + c8];
    *(bf16x8*)&tile[r][c8] = v;
  }
  __syncthreads();
#pragma unroll
  for (int it = 0; it < 2; ++it) {
    int vi = it * 256 + tid;
    int d = vi >> 3, s8 = (vi & 7) * 8;
    bf16x8 o;
#pragma unroll
    for (int j = 0; j < 8; ++j) o[j] = tile[s8 + j][d];
    *(bf16x8*)&vtb[((size_t)bh * HDQ + d0 + d) * SQ + s0 + s8] = o;
  }
}

// ---------- 128x128 B^T GEMM (m97 structure). MODE 0: QKV -> [B,H,S,HD] bf16 (z picks W/out).
// MODE 1: -> fp32 linear [M][N]. ----------
template <int MODE>
__global__ __launch_bounds__(256, 2) void gemm_bt(const short* __restrict__ A,
                                                  const short* __restrict__ W,
                                                  short* __restrict__ oQ, short* __restrict__ oK,
                                                  short* __restrict__ oV, float* __restrict__ oF) {
  const int K = DQ;
  __shared__ __align__(16) short As[128 * 32];
  __shared__ __align__(16) short Bs[128 * 32];
  int n0 = blockIdx.x * 128, m0 = blockIdx.y * 128;
  const short* Bw = (MODE == 0) ? (W + (size_t)blockIdx.z * DQ * DQ) : W;
  int tid = threadIdx.x, w = tid >> 6, lane = tid & 63;
  int wr = w >> 1, wc = w & 1;
  int ar = lane >> 2, acol = (lane & 3) * 8;
  f32x4 acc[4][4] = {};
  int lra = wr * 64 + (lane & 15), lrb = wc * 64 + (lane & 15), kc = (lane >> 4) * 8;
  for (int k0 = 0; k0 < K; k0 += 32) {
    __syncthreads();
#pragma unroll
    for (int i = 0; i < 2; ++i) {
      int c = w * 2 + i;
      int r = c * 16 + ar;
      gload_lds16(A + (size_t)(m0 + r) * K + k0 + acol, &As[c * 512]);
      gload_lds16(Bw + (size_t)(n0 + r) * K + k0 + acol, &Bs[c * 512]);
    }
    __syncthreads();
    bf16x8 af[4], bfr[4];
#pragma unroll
    for (int f = 0; f < 4; ++f) {
      af[f] = *(const bf16x8*)&As[(lra + f * 16) * 32 + kc];
      bfr[f] = *(const bf16x8*)&Bs[(lrb + f * 16) * 32 + kc];
    }
#pragma unroll
    for (int mf = 0; mf < 4; ++mf)
#pragma unroll
      for (int nf = 0; nf < 4; ++nf)
        acc[mf][nf] = __builtin_amdgcn_mfma_f32_16x16x32_bf16(af[mf], bfr[nf], acc[mf][nf], 0, 0, 0);
  }
  short* oT = nullptr;
  if (MODE == 0) oT = (blockIdx.z == 0) ? oQ : (blockIdx.z == 1) ? oK : oV;
#pragma unroll
  for (int mf = 0; mf < 4; ++mf) {
    int mb = m0 + wr * 64 + mf * 16 + (lane >> 4) * 4;
#pragma unroll
    for (int nf = 0; nf < 4; ++nf) {
      int n = n0 + wc * 64 + nf * 16 + (lane & 15);
#pragma unroll
      for (int j = 0; j < 4; ++j) {
        int m = mb + j;
        float v = acc[mf][nf][j];
        if (MODE == 0) {
          int b = m >> 11, s = m & 2047, h = n >> 7, hd = n & 127;
          oT[(((size_t)(b * HQ + h)) * SQ + s) * HDQ + hd] = f2bf(v);
        } else {
          oF[(size_t)m * DQ + n] = v;
        }
      }
    }
  }
}

// ---------- Flash attention v3: no K/V staging, zero barriers ----------
// 512 blocks = 16 x * 32 bh; qt = x (bh<16) or 15-x (bh>=16) so the two blocks
// co-resident on a CU have complementary work (36 kv-steps total). 4 waves x 32
// q-rows. K and V^T fragments loaded straight from global (L2-resident). Softmax
// in exp2 domain; denominator reduced once at the end.
__global__ __launch_bounds__(256, 2) void flash_kernel(const short* __restrict__ qb,
                                                       const short* __restrict__ kb,
                                                       const short* __restrict__ vtb,
                                                       short* __restrict__ ab) {
  __shared__ __align__(16) short Pl[4][32 * 72];
  int x = blockIdx.x, bh = blockIdx.y;
  int qt = (bh & 16) ? (15 - x) : x;
  int q0 = qt * 128;
  int tid = threadIdx.x, w = tid >> 6, lane = tid & 63;
  const short* qbase = qb + (size_t)bh * SQ * HDQ;
  const short* kbase = kb + (size_t)bh * SQ * HDQ;
  const short* vbase = vtb + (size_t)bh * HDQ * SQ;
  int b = bh >> 4, h = bh & 15;

  bf16x8 qf[2][4];
  {
    int qr = q0 + w * 32 + (lane & 15);
    int kq = (lane >> 4) * 8;
#pragma unroll
    for (int i = 0; i < 2; ++i)
#pragma unroll
      for (int c = 0; c < 4; ++c)
        qf[i][c] = *(const bf16x8*)&qbase[(size_t)(qr + i * 16) * HDQ + c * 32 + kq];
  }
  f32x4 oacc[2][8] = {};
  f32x4 m_st[2], l_st[2];
#pragma unroll
  for (int i = 0; i < 2; ++i) {
    m_st[i] = f32x4{-1e30f, -1e30f, -1e30f, -1e30f};
    l_st[i] = f32x4{0.f, 0.f, 0.f, 0.f};
  }
  int nt = 2 * qt + 2;
#pragma unroll 1
  for (int t = 0; t < nt; ++t) {
    int k0 = t * 64;
    // ---- QK^T: K fragments direct from global ----
    f32x4 sacc[2][4] = {};
    __builtin_amdgcn_s_setprio(1);
#pragma unroll
    for (int nf = 0; nf < 4; ++nf) {
      int rk = k0 + nf * 16 + (lane & 15);
#pragma unroll
      for (int cc = 0; cc < 4; ++cc) {
        int ck = cc * 32 + (lane >> 4) * 8;
        bf16x8 kf = *(const bf16x8*)&kbase[(size_t)rk * HDQ + ck];
        sacc[0][nf] = __builtin_amdgcn_mfma_f32_16x16x32_bf16(qf[0][cc], kf, sacc[0][nf], 0, 0, 0);
        sacc[1][nf] = __builtin_amdgcn_mfma_f32_16x16x32_bf16(qf[1][cc], kf, sacc[1][nf], 0, 0, 0);
      }
    }
    __builtin_amdgcn_s_setprio(0);
    if (k0 + 63 > q0) {
#pragma unroll
      for (int i = 0; i < 2; ++i)
#pragma unroll
        for (int nf = 0; nf < 4; ++nf)
#pragma unroll
          for (int j = 0; j < 4; ++j) {
            int q = q0 + w * 32 + i * 16 + (lane >> 4) * 4 + j;
            int k = k0 + nf * 16 + (lane & 15);
            if (k > q) sacc[i][nf][j] -= 1e9f;
          }
    }
#pragma unroll
    for (int i = 0; i < 2; ++i) {
      f32x4 mt = sacc[i][0];
#pragma unroll
      for (int nf = 1; nf < 4; ++nf)
#pragma unroll
        for (int j = 0; j < 4; ++j) mt[j] = fmaxf(mt[j], sacc[i][nf][j]);
#pragma unroll
      for (int d = 1; d < 16; d <<= 1)
#pragma unroll
        for (int j = 0; j < 4; ++j) mt[j] = fmaxf(mt[j], __shfl_xor(mt[j], d));
      f32x4 mn, al;
#pragma unroll
      for (int j = 0; j < 4; ++j) {
        mn[j] = fmaxf(m_st[i][j], mt[j]);
        al[j] = exp2f(m_st[i][j] - mn[j]);
      }
#pragma unroll
      for (int df = 0; df < 8; ++df) oacc[i][df] *= al;
#pragma unroll
      for (int nf = 0; nf < 4; ++nf)
#pragma unroll
        for (int j = 0; j < 4; ++j) {
          float p = exp2f(sacc[i][nf][j] - mn[j]);
          l_st[i][j] = l_st[i][j] * ((nf == 0) ? al[j] : 1.0f) + p;
          Pl[w][(i * 16 + (lane >> 4) * 4 + j) * 72 + nf * 16 + (lane & 15)] = f2bf(p);
        }
      m_st[i] = mn;
    }
    // ---- PV: V^T fragments direct from global ----
    __builtin_amdgcn_s_setprio(1);
#pragma unroll
    for (int cc = 0; cc < 2; ++cc) {
      bf16x8 pf0 = *(const bf16x8*)&Pl[w][((lane & 15)) * 72 + cc * 32 + (lane >> 4) * 8];
      bf16x8 pf1 = *(const bf16x8*)&Pl[w][(16 + (lane & 15)) * 72 + cc * 32 + (lane >> 4) * 8];
#pragma unroll
      for (int df = 0; df < 8; ++df) {
        int rd = df * 16 + (lane & 15);
        int cv = k0 + cc * 32 + (lane >> 4) * 8;
        bf16x8 vf = *(const bf16x8*)&vbase[(size_t)rd * SQ + cv];
        oacc[0][df] = __builtin_amdgcn_mfma_f32_16x16x32_bf16(pf0, vf, oacc[0][df], 0, 0, 0);
        oacc[1][df] = __builtin_amdgcn_mfma_f32_16x16x32_bf16(pf1, vf, oacc[1][df], 0, 0, 0);
      }
    }
    __builtin_amdgcn_s_setprio(0);
  }
#pragma unroll
  for (int i = 0; i < 2; ++i) {
#pragma unroll
    for (int d = 1; d < 16; d <<= 1)
#pragma unroll
      for (int j = 0; j < 4; ++j) l_st[i][j] += __shfl_xor(l_st[i][j], d);
    f32x4 inv;
#pragma unroll
    for (int j = 0; j < 4; ++j) inv[j] = 1.0f / l_st[i][j];
#pragma unroll
    for (int df = 0; df < 8; ++df)
#pragma unroll
      for (int j = 0; j < 4; ++j) {
        int q = q0 + w * 32 + i * 16 + (lane >> 4) * 4 + j;
        int dd = df * 16 + (lane & 15);
        ab[((size_t)b * SQ + q) * DQ + h * HDQ + dd] = f2bf(oacc[i][df][j] * inv[j]);
      }
  }
}

extern "C" void kernel_launch(void* const* d_in, const int* in_sizes, int n_in,
                              void* d_out, int out_size, void* d_ws, size_t ws_size,
                              hipStream_t stream) {
  (void)in_sizes; (void)n_in; (void)out_size; (void)ws_size;
  const float* x  = (const float*)d_in[0];
  const float* wq = (const float*)d_in[1];
  const float* wk = (const float*)d_in[2];
  const float* wv = (const float*)d_in[3];
  const float* wo = (const float*)d_in[4];
  const float* fc = (const float*)d_in[5];
  const float* fs = (const float*)d_in[6];
  // d_in[7] = mask (implemented analytically: causal, start_pos=0), d_in[8] = start_pos
  float* out = (float*)d_out;

  short* xb  = (short*)d_ws;              // 8,388,608 elems
  short* wqb = xb + (size_t)8388608;      // 4 weights, 4,194,304 each
  short* wkb = wqb + (size_t)4194304;
  short* wvb = wkb + (size_t)4194304;
  short* wob = wvb + (size_t)4194304;
  short* qb  = wob + (size_t)4194304;     // [B,H,S,HD] bf16
  short* kb  = qb + (size_t)8388608;
  short* ab  = kb + (size_t)8388608;      // attn out [B,S,D] bf16
  // V and V^T overlaid into d_out (33.5 MB, dead before final GEMM writes it)
  short* vb  = (short*)d_out;
  short* vtb = vb + (size_t)8388608;

  cvt_kernel<<<4096, 256, 0, stream>>>(x, xb, 1048576);
  cvt_kernel<<<2048, 256, 0, stream>>>(wq, wqb, 524288);
  cvt_kernel<<<2048, 256, 0, stream>>>(wk, wkb, 524288);
  cvt_kernel<<<2048, 256, 0, stream>>>(wv, wvb, 524288);
  cvt_kernel<<<2048, 256, 0, stream>>>(wo, wob, 524288);

  gemm_bt<0><<<dim3(16, 32, 3), 256, 0, stream>>>(xb, wqb, qb, kb, vb, nullptr);

  // Q scale = log2(e)/sqrt(HD) so flash softmax runs in exp2 domain
  rope_kernel<<<4096, 256, 0, stream>>>(qb, fc, fs, 0.12751744779976827f, 1048576);
  rope_kernel<<<4096, 256, 0, stream>>>(kb, fc, fs, 1.0f, 1048576);

  vtrans_kernel<<<dim3(2, 32, 32), 256, 0, stream>>>(vb, vtb);

  flash_kernel<<<dim3(16, 32), 256, 0, stream>>>(qb, kb, vtb, ab);

  gemm_bt<1><<<dim3(16, 32, 1), 256, 0, stream>>>(ab, wob, nullptr, nullptr, nullptr, out);
}

// Round 4
// 334.262 us; speedup vs baseline: 1.1928x; 1.1928x over previous
//
#include <hip/hip_runtime.h>

// Attention layer, MI355X. Internal bf16 MFMA compute (tolerance 7e-2 permits).
// Pipeline: cvt -> fused QKV GEMM -> RoPE -> V-transpose -> flash attn -> out GEMM.
// R4: flash = R2's dbuf+vmcnt(8) structure, but 16 q-rows/wave (64-row q-tile),
// LDS 72.5KB -> 2 blocks/CU, 1024 blocks with per-XCD-balanced complementary
// pairing qt=(bh&8)?31-x:x. Inter-block overlap hides the stage drain.

#define SQ 2048
#define DQ 2048
#define HQ 16
#define HDQ 128

typedef short bf16x8 __attribute__((ext_vector_type(8)));
typedef float f32x4 __attribute__((ext_vector_type(4)));

#define WAITVM8 asm volatile("s_waitcnt vmcnt(8)" ::: "memory")
#define WAITVM0 asm volatile("s_waitcnt vmcnt(0)" ::: "memory")

__device__ __forceinline__ short f2bf(float f) {
  union { float f; unsigned u; } v; v.f = f;
  unsigned r = (v.u + 0x7FFFu + ((v.u >> 16) & 1u)) >> 16;
  return (short)r;
}
__device__ __forceinline__ float bf2f(short b) {
  union { unsigned u; float f; } v; v.u = ((unsigned)(unsigned short)b) << 16;
  return v.f;
}
__device__ __forceinline__ void gload_lds16(const void* g, void* l) {
  __builtin_amdgcn_global_load_lds(
      (const __attribute__((address_space(1))) void*)g,
      (__attribute__((address_space(3))) void*)l, 16, 0, 0);
}

// ---------- fp32 -> bf16 (8 elems/thread) ----------
__global__ void cvt_kernel(const float* __restrict__ in, short* __restrict__ out, int nvec) {
  int i = blockIdx.x * blockDim.x + threadIdx.x;
  if (i >= nvec) return;
  const f32x4* p = (const f32x4*)in + (size_t)i * 2;
  f32x4 a = p[0], b = p[1];
  bf16x8 o;
  o[0] = f2bf(a[0]); o[1] = f2bf(a[1]); o[2] = f2bf(a[2]); o[3] = f2bf(a[3]);
  o[4] = f2bf(b[0]); o[5] = f2bf(b[1]); o[6] = f2bf(b[2]); o[7] = f2bf(b[3]);
  *((bf16x8*)out + i) = o;
}

// ---------- RoPE in-place on [BH, S, HD] bf16, pairs (2i,2i+1), + optional scale ----------
__global__ void rope_kernel(short* __restrict__ t, const float* __restrict__ cosT,
                            const float* __restrict__ sinT, float scale, int nvec) {
  int i = blockIdx.x * blockDim.x + threadIdx.x;
  if (i >= nvec) return;
  size_t off = (size_t)i * 8;
  int hd0 = (int)(off & 127);
  int s = (int)((off >> 7) & 2047);
  bf16x8 v = *((const bf16x8*)(t + off));
  f32x4 c  = *(const f32x4*)(cosT + (size_t)s * 64 + (hd0 >> 1));
  f32x4 sn = *(const f32x4*)(sinT + (size_t)s * 64 + (hd0 >> 1));
  bf16x8 o;
#pragma unroll
  for (int p = 0; p < 4; ++p) {
    float xr = bf2f(v[2 * p]), xi = bf2f(v[2 * p + 1]);
    o[2 * p]     = f2bf((xr * c[p] - xi * sn[p]) * scale);
    o[2 * p + 1] = f2bf((xr * sn[p] + xi * c[p]) * scale);
  }
  *((bf16x8*)(t + off)) = o;
}

// ---------- V [BH,S,HD] -> V^T [BH,HD,S] ----------
__global__ void vtrans_kernel(const short* __restrict__ vb, short* __restrict__ vtb) {
  __shared__ __align__(16) short tile[64][72];
  int bh = blockIdx.z, s0 = blockIdx.y * 64, d0 = blockIdx.x * 64;
  int tid = threadIdx.x;
#pragma unroll
  for (int it = 0; it < 2; ++it) {
    int vi = it * 256 + tid;
    int r = vi >> 3, c8 = (vi & 7) * 8;
    bf16x8 v = *(const bf16x8*)&vb[((size_t)bh * SQ + s0 + r) * HDQ + d0 + c8];
    *(bf16x8*)&tile[r][c8] = v;
  }
  __syncthreads();
#pragma unroll
  for (int it = 0; it < 2; ++it) {
    int vi = it * 256 + tid;
    int d = vi >> 3, s8 = (vi & 7) * 8;
    bf16x8 o;
#pragma unroll
    for (int j = 0; j < 8; ++j) o[j] = tile[s8 + j][d];
    *(bf16x8*)&vtb[((size_t)bh * HDQ + d0 + d) * SQ + s0 + s8] = o;
  }
}

// ---------- 128x128 B^T GEMM (m97 structure). MODE 0: QKV -> [B,H,S,HD] bf16 (z picks W/out).
// MODE 1: -> fp32 linear [M][N]. ----------
template <int MODE>
__global__ __launch_bounds__(256, 2) void gemm_bt(const short* __restrict__ A,
                                                  const short* __restrict__ W,
                                                  short* __restrict__ oQ, short* __restrict__ oK,
                                                  short* __restrict__ oV, float* __restrict__ oF) {
  const int K = DQ;
  __shared__ __align__(16) short As[128 * 32];
  __shared__ __align__(16) short Bs[128 * 32];
  int n0 = blockIdx.x * 128, m0 = blockIdx.y * 128;
  const short* Bw = (MODE == 0) ? (W + (size_t)blockIdx.z * DQ * DQ) : W;
  int tid = threadIdx.x, w = tid >> 6, lane = tid & 63;
  int wr = w >> 1, wc = w & 1;
  int ar = lane >> 2, acol = (lane & 3) * 8;
  f32x4 acc[4][4] = {};
  int lra = wr * 64 + (lane & 15), lrb = wc * 64 + (lane & 15), kc = (lane >> 4) * 8;
  for (int k0 = 0; k0 < K; k0 += 32) {
    __syncthreads();
#pragma unroll
    for (int i = 0; i < 2; ++i) {
      int c = w * 2 + i;
      int r = c * 16 + ar;
      gload_lds16(A + (size_t)(m0 + r) * K + k0 + acol, &As[c * 512]);
      gload_lds16(Bw + (size_t)(n0 + r) * K + k0 + acol, &Bs[c * 512]);
    }
    __syncthreads();
    bf16x8 af[4], bfr[4];
#pragma unroll
    for (int f = 0; f < 4; ++f) {
      af[f] = *(const bf16x8*)&As[(lra + f * 16) * 32 + kc];
      bfr[f] = *(const bf16x8*)&Bs[(lrb + f * 16) * 32 + kc];
    }
#pragma unroll
    for (int mf = 0; mf < 4; ++mf)
#pragma unroll
      for (int nf = 0; nf < 4; ++nf)
        acc[mf][nf] = __builtin_amdgcn_mfma_f32_16x16x32_bf16(af[mf], bfr[nf], acc[mf][nf], 0, 0, 0);
  }
  short* oT = nullptr;
  if (MODE == 0) oT = (blockIdx.z == 0) ? oQ : (blockIdx.z == 1) ? oK : oV;
#pragma unroll
  for (int mf = 0; mf < 4; ++mf) {
    int mb = m0 + wr * 64 + mf * 16 + (lane >> 4) * 4;
#pragma unroll
    for (int nf = 0; nf < 4; ++nf) {
      int n = n0 + wc * 64 + nf * 16 + (lane & 15);
#pragma unroll
      for (int j = 0; j < 4; ++j) {
        int m = mb + j;
        float v = acc[mf][nf][j];
        if (MODE == 0) {
          int b = m >> 11, s = m & 2047, h = n >> 7, hd = n & 127;
          oT[(((size_t)(b * HQ + h)) * SQ + s) * HDQ + hd] = f2bf(v);
        } else {
          oF[(size_t)m * DQ + n] = v;
        }
      }
    }
  }
}

// ---------- Flash attention R4: dbuf LDS staging, 16 q-rows/wave ----------
// 1024 blocks = 32 x * 32 bh; qt = (bh&8)? 31-x : x (per-XCD work sums to a
// constant). 64-row q-tile, 4 waves x 16 rows. K/V double-buffered via
// global_load_lds + XOR swizzle; raw s_barrier + counted vmcnt(8). exp2 softmax.
__device__ __forceinline__ void stage_kv(const short* kbase, const short* vbase, int k0,
                                         short* KsB, short* VtB, int w, int lane) {
#pragma unroll
  for (int i = 0; i < 4; ++i) {
    int c = w * 4 + i;
    int r = c * 4 + (lane >> 4);
    int col = (lane & 15) * 8;
    gload_lds16(kbase + (size_t)(k0 + r) * HDQ + (col ^ ((r & 7) << 3)), KsB + c * 512);
    int d = c * 8 + (lane >> 3);
    int jj = (lane & 7) * 8;
    gload_lds16(vbase + (size_t)d * SQ + k0 + (jj ^ ((d & 7) << 3)), VtB + c * 512);
  }
}

__global__ __launch_bounds__(256, 2) void flash_kernel(const short* __restrict__ qb,
                                                       const short* __restrict__ kb,
                                                       const short* __restrict__ vtb,
                                                       short* __restrict__ ab) {
  __shared__ __align__(16) short Ks[2][64 * 128];
  __shared__ __align__(16) short Vt[2][128 * 64];
  __shared__ __align__(16) short Pl[4][16 * 68];
  int x = blockIdx.x, bh = blockIdx.y;
  int qt = (bh & 8) ? (31 - x) : x;
  int q0 = qt * 64;
  int tid = threadIdx.x, w = tid >> 6, lane = tid & 63;
  const short* qbase = qb + (size_t)bh * SQ * HDQ;
  const short* kbase = kb + (size_t)bh * SQ * HDQ;
  const short* vbase = vtb + (size_t)bh * HDQ * SQ;
  int b = bh >> 4, h = bh & 15;

  bf16x8 qf[4];
  {
    int qr = q0 + w * 16 + (lane & 15);
    int kq = (lane >> 4) * 8;
#pragma unroll
    for (int c = 0; c < 4; ++c)
      qf[c] = *(const bf16x8*)&qbase[(size_t)qr * HDQ + c * 32 + kq];
  }
  f32x4 oacc[8] = {};
  f32x4 m_st = f32x4{-1e30f, -1e30f, -1e30f, -1e30f};
  f32x4 l_st = f32x4{0.f, 0.f, 0.f, 0.f};
  int nt = qt + 1;
  stage_kv(kbase, vbase, 0, Ks[0], Vt[0], w, lane);
#pragma unroll 1
  for (int t = 0; t < nt; ++t) {
    int cur = t & 1;
    int k0 = t * 64;
    __builtin_amdgcn_s_barrier();  // A: all waves done reading buf cur^1
    if (t + 1 < nt) {
      stage_kv(kbase, vbase, (t + 1) * 64, Ks[cur ^ 1], Vt[cur ^ 1], w, lane);
      WAITVM8;  // current tile's 8 loads landed; next tile's stay in flight
    } else {
      WAITVM0;
    }
    __builtin_amdgcn_s_barrier();  // B: all waves' current loads landed
    f32x4 sacc[4] = {};
    __builtin_amdgcn_s_setprio(1);
#pragma unroll
    for (int nf = 0; nf < 4; ++nf) {
      int rk = nf * 16 + (lane & 15);
#pragma unroll
      for (int cc = 0; cc < 4; ++cc) {
        int ck = cc * 32 + (lane >> 4) * 8;
        bf16x8 kf = *(const bf16x8*)&Ks[cur][rk * 128 + (ck ^ ((rk & 7) << 3))];
        sacc[nf] = __builtin_amdgcn_mfma_f32_16x16x32_bf16(qf[cc], kf, sacc[nf], 0, 0, 0);
      }
    }
    __builtin_amdgcn_s_setprio(0);
    if (t == nt - 1) {  // only the diagonal tile needs masking
#pragma unroll
      for (int nf = 0; nf < 4; ++nf)
#pragma unroll
        for (int j = 0; j < 4; ++j) {
          int q = q0 + w * 16 + (lane >> 4) * 4 + j;
          int k = k0 + nf * 16 + (lane & 15);
          if (k > q) sacc[nf][j] -= 1e9f;
        }
    }
    f32x4 mt = sacc[0];
#pragma unroll
    for (int nf = 1; nf < 4; ++nf)
#pragma unroll
      for (int j = 0; j < 4; ++j) mt[j] = fmaxf(mt[j], sacc[nf][j]);
#pragma unroll
    for (int d = 1; d < 16; d <<= 1)
#pragma unroll
      for (int j = 0; j < 4; ++j) mt[j] = fmaxf(mt[j], __shfl_xor(mt[j], d));
    f32x4 mn, al;
#pragma unroll
    for (int j = 0; j < 4; ++j) {
      mn[j] = fmaxf(m_st[j], mt[j]);
      al[j] = exp2f(m_st[j] - mn[j]);
    }
#pragma unroll
    for (int df = 0; df < 8; ++df) oacc[df] *= al;
#pragma unroll
    for (int nf = 0; nf < 4; ++nf)
#pragma unroll
      for (int j = 0; j < 4; ++j) {
        float p = exp2f(sacc[nf][j] - mn[j]);
        l_st[j] = l_st[j] * ((nf == 0) ? al[j] : 1.0f) + p;
        Pl[w][((lane >> 4) * 4 + j) * 68 + nf * 16 + (lane & 15)] = f2bf(p);
      }
    m_st = mn;
    __builtin_amdgcn_s_setprio(1);
#pragma unroll
    for (int cc = 0; cc < 2; ++cc) {
      bf16x8 pf = *(const bf16x8*)&Pl[w][(lane & 15) * 68 + cc * 32 + (lane >> 4) * 8];
#pragma unroll
      for (int df = 0; df < 8; ++df) {
        int rd = df * 16 + (lane & 15);
        int cv = cc * 32 + (lane >> 4) * 8;
        bf16x8 vf = *(const bf16x8*)&Vt[cur][rd * 64 + (cv ^ ((rd & 7) << 3))];
        oacc[df] = __builtin_amdgcn_mfma_f32_16x16x32_bf16(pf, vf, oacc[df], 0, 0, 0);
      }
    }
    __builtin_amdgcn_s_setprio(0);
  }
#pragma unroll
  for (int d = 1; d < 16; d <<= 1)
#pragma unroll
    for (int j = 0; j < 4; ++j) l_st[j] += __shfl_xor(l_st[j], d);
  f32x4 inv;
#pragma unroll
  for (int j = 0; j < 4; ++j) inv[j] = 1.0f / l_st[j];
#pragma unroll
  for (int df = 0; df < 8; ++df)
#pragma unroll
    for (int j = 0; j < 4; ++j) {
      int q = q0 + w * 16 + (lane >> 4) * 4 + j;
      int dd = df * 16 + (lane & 15);
      ab[((size_t)b * SQ + q) * DQ + h * HDQ + dd] = f2bf(oacc[df][j] * inv[j]);
    }
}

extern "C" void kernel_launch(void* const* d_in, const int* in_sizes, int n_in,
                              void* d_out, int out_size, void* d_ws, size_t ws_size,
                              hipStream_t stream) {
  (void)in_sizes; (void)n_in; (void)out_size; (void)ws_size;
  const float* x  = (const float*)d_in[0];
  const float* wq = (const float*)d_in[1];
  const float* wk = (const float*)d_in[2];
  const float* wv = (const float*)d_in[3];
  const float* wo = (const float*)d_in[4];
  const float* fc = (const float*)d_in[5];
  const float* fs = (const float*)d_in[6];
  // d_in[7] = mask (implemented analytically: causal, start_pos=0), d_in[8] = start_pos
  float* out = (float*)d_out;

  short* xb  = (short*)d_ws;              // 8,388,608 elems
  short* wqb = xb + (size_t)8388608;      // 4 weights, 4,194,304 each
  short* wkb = wqb + (size_t)4194304;
  short* wvb = wkb + (size_t)4194304;
  short* wob = wvb + (size_t)4194304;
  short* qb  = wob + (size_t)4194304;     // [B,H,S,HD] bf16
  short* kb  = qb + (size_t)8388608;
  short* ab  = kb + (size_t)8388608;      // attn out [B,S,D] bf16
  // V and V^T overlaid into d_out (33.5 MB, dead before final GEMM writes it)
  short* vb  = (short*)d_out;
  short* vtb = vb + (size_t)8388608;

  cvt_kernel<<<4096, 256, 0, stream>>>(x, xb, 1048576);
  cvt_kernel<<<2048, 256, 0, stream>>>(wq, wqb, 524288);
  cvt_kernel<<<2048, 256, 0, stream>>>(wk, wkb, 524288);
  cvt_kernel<<<2048, 256, 0, stream>>>(wv, wvb, 524288);
  cvt_kernel<<<2048, 256, 0, stream>>>(wo, wob, 524288);

  gemm_bt<0><<<dim3(16, 32, 3), 256, 0, stream>>>(xb, wqb, qb, kb, vb, nullptr);

  // Q scale = log2(e)/sqrt(HD) so flash softmax runs in exp2 domain
  rope_kernel<<<4096, 256, 0, stream>>>(qb, fc, fs, 0.12751744779976827f, 1048576);
  rope_kernel<<<4096, 256, 0, stream>>>(kb, fc, fs, 1.0f, 1048576);

  vtrans_kernel<<<dim3(2, 32, 32), 256, 0, stream>>>(vb, vtb);

  flash_kernel<<<dim3(32, 32), 256, 0, stream>>>(qb, kb, vtb, ab);

  gemm_bt<1><<<dim3(16, 32, 1), 256, 0, stream>>>(ab, wob, nullptr, nullptr, nullptr, out);
}

// Round 5
// 308.789 us; speedup vs baseline: 1.2912x; 1.0825x over previous
//
#include <hip/hip_runtime.h>

// Attention layer, MI355X. Internal bf16 MFMA compute (tolerance 7e-2 permits).
// Pipeline: cvt -> fused QKV GEMM -> RoPE -> V-transpose -> flash attn -> out GEMM.
// R5 flash: KVBLK=32 dbuf (LDS 36KB -> 4 blocks/CU = 4 waves/SIMD), swapped QK^T
// (mfma(K,Q): softmax state scalar per lane, 2-shfl reduce, packed b64 P-writes),
// per-wave skip of fully-masked tiles. Counted vmcnt(4) keeps prefetch in flight.

#define SQ 2048
#define DQ 2048
#define HQ 16
#define HDQ 128

typedef short bf16x8 __attribute__((ext_vector_type(8)));
typedef short bf16x4 __attribute__((ext_vector_type(4)));
typedef float f32x4 __attribute__((ext_vector_type(4)));

#define WAITVM4 asm volatile("s_waitcnt vmcnt(4)" ::: "memory")
#define WAITVM0 asm volatile("s_waitcnt vmcnt(0)" ::: "memory")

__device__ __forceinline__ short f2bf(float f) {
  union { float f; unsigned u; } v; v.f = f;
  unsigned r = (v.u + 0x7FFFu + ((v.u >> 16) & 1u)) >> 16;
  return (short)r;
}
__device__ __forceinline__ float bf2f(short b) {
  union { unsigned u; float f; } v; v.u = ((unsigned)(unsigned short)b) << 16;
  return v.f;
}
__device__ __forceinline__ void gload_lds16(const void* g, void* l) {
  __builtin_amdgcn_global_load_lds(
      (const __attribute__((address_space(1))) void*)g,
      (__attribute__((address_space(3))) void*)l, 16, 0, 0);
}

// ---------- fp32 -> bf16 (8 elems/thread) ----------
__global__ void cvt_kernel(const float* __restrict__ in, short* __restrict__ out, int nvec) {
  int i = blockIdx.x * blockDim.x + threadIdx.x;
  if (i >= nvec) return;
  const f32x4* p = (const f32x4*)in + (size_t)i * 2;
  f32x4 a = p[0], b = p[1];
  bf16x8 o;
  o[0] = f2bf(a[0]); o[1] = f2bf(a[1]); o[2] = f2bf(a[2]); o[3] = f2bf(a[3]);
  o[4] = f2bf(b[0]); o[5] = f2bf(b[1]); o[6] = f2bf(b[2]); o[7] = f2bf(b[3]);
  *((bf16x8*)out + i) = o;
}

// ---------- RoPE in-place on [BH, S, HD] bf16, pairs (2i,2i+1), + optional scale ----------
__global__ void rope_kernel(short* __restrict__ t, const float* __restrict__ cosT,
                            const float* __restrict__ sinT, float scale, int nvec) {
  int i = blockIdx.x * blockDim.x + threadIdx.x;
  if (i >= nvec) return;
  size_t off = (size_t)i * 8;
  int hd0 = (int)(off & 127);
  int s = (int)((off >> 7) & 2047);
  bf16x8 v = *((const bf16x8*)(t + off));
  f32x4 c  = *(const f32x4*)(cosT + (size_t)s * 64 + (hd0 >> 1));
  f32x4 sn = *(const f32x4*)(sinT + (size_t)s * 64 + (hd0 >> 1));
  bf16x8 o;
#pragma unroll
  for (int p = 0; p < 4; ++p) {
    float xr = bf2f(v[2 * p]), xi = bf2f(v[2 * p + 1]);
    o[2 * p]     = f2bf((xr * c[p] - xi * sn[p]) * scale);
    o[2 * p + 1] = f2bf((xr * sn[p] + xi * c[p]) * scale);
  }
  *((bf16x8*)(t + off)) = o;
}

// ---------- V [BH,S,HD] -> V^T [BH,HD,S] ----------
__global__ void vtrans_kernel(const short* __restrict__ vb, short* __restrict__ vtb) {
  __shared__ __align__(16) short tile[64][72];
  int bh = blockIdx.z, s0 = blockIdx.y * 64, d0 = blockIdx.x * 64;
  int tid = threadIdx.x;
#pragma unroll
  for (int it = 0; it < 2; ++it) {
    int vi = it * 256 + tid;
    int r = vi >> 3, c8 = (vi & 7) * 8;
    bf16x8 v = *(const bf16x8*)&vb[((size_t)bh * SQ + s0 + r) * HDQ + d0 + c8];
    *(bf16x8*)&tile[r][c8] = v;
  }
  __syncthreads();
#pragma unroll
  for (int it = 0; it < 2; ++it) {
    int vi = it * 256 + tid;
    int d = vi >> 3, s8 = (vi & 7) * 8;
    bf16x8 o;
#pragma unroll
    for (int j = 0; j < 8; ++j) o[j] = tile[s8 + j][d];
    *(bf16x8*)&vtb[((size_t)bh * HDQ + d0 + d) * SQ + s0 + s8] = o;
  }
}

// ---------- 128x128 B^T GEMM (m97 structure). MODE 0: QKV -> [B,H,S,HD] bf16 (z picks W/out).
// MODE 1: -> fp32 linear [M][N]. ----------
template <int MODE>
__global__ __launch_bounds__(256, 2) void gemm_bt(const short* __restrict__ A,
                                                  const short* __restrict__ W,
                                                  short* __restrict__ oQ, short* __restrict__ oK,
                                                  short* __restrict__ oV, float* __restrict__ oF) {
  const int K = DQ;
  __shared__ __align__(16) short As[128 * 32];
  __shared__ __align__(16) short Bs[128 * 32];
  int n0 = blockIdx.x * 128, m0 = blockIdx.y * 128;
  const short* Bw = (MODE == 0) ? (W + (size_t)blockIdx.z * DQ * DQ) : W;
  int tid = threadIdx.x, w = tid >> 6, lane = tid & 63;
  int wr = w >> 1, wc = w & 1;
  int ar = lane >> 2, acol = (lane & 3) * 8;
  f32x4 acc[4][4] = {};
  int lra = wr * 64 + (lane & 15), lrb = wc * 64 + (lane & 15), kc = (lane >> 4) * 8;
  for (int k0 = 0; k0 < K; k0 += 32) {
    __syncthreads();
#pragma unroll
    for (int i = 0; i < 2; ++i) {
      int c = w * 2 + i;
      int r = c * 16 + ar;
      gload_lds16(A + (size_t)(m0 + r) * K + k0 + acol, &As[c * 512]);
      gload_lds16(Bw + (size_t)(n0 + r) * K + k0 + acol, &Bs[c * 512]);
    }
    __syncthreads();
    bf16x8 af[4], bfr[4];
#pragma unroll
    for (int f = 0; f < 4; ++f) {
      af[f] = *(const bf16x8*)&As[(lra + f * 16) * 32 + kc];
      bfr[f] = *(const bf16x8*)&Bs[(lrb + f * 16) * 32 + kc];
    }
#pragma unroll
    for (int mf = 0; mf < 4; ++mf)
#pragma unroll
      for (int nf = 0; nf < 4; ++nf)
        acc[mf][nf] = __builtin_amdgcn_mfma_f32_16x16x32_bf16(af[mf], bfr[nf], acc[mf][nf], 0, 0, 0);
  }
  short* oT = nullptr;
  if (MODE == 0) oT = (blockIdx.z == 0) ? oQ : (blockIdx.z == 1) ? oK : oV;
#pragma unroll
  for (int mf = 0; mf < 4; ++mf) {
    int mb = m0 + wr * 64 + mf * 16 + (lane >> 4) * 4;
#pragma unroll
    for (int nf = 0; nf < 4; ++nf) {
      int n = n0 + wc * 64 + nf * 16 + (lane & 15);
#pragma unroll
      for (int j = 0; j < 4; ++j) {
        int m = mb + j;
        float v = acc[mf][nf][j];
        if (MODE == 0) {
          int b = m >> 11, s = m & 2047, h = n >> 7, hd = n & 127;
          oT[(((size_t)(b * HQ + h)) * SQ + s) * HDQ + hd] = f2bf(v);
        } else {
          oF[(size_t)m * DQ + n] = v;
        }
      }
    }
  }
}

// ---------- Flash attention R5: KVBLK=32 dbuf, swapped QK^T, 4 blocks/CU ----------
// 1024 blocks = 32 x * 32 bh; qt = (bh&8)? 31-x : x. 64-row q-tile, 4 waves x 16 rows.
// S^T = mfma(K,Q): lane owns q = qw0+(lane&15); m/l scalar per lane; 2-shfl reduce;
// P packed to LDS via 2x ds_write_b64 (XOR-swizzled, ~conflict-free); PV reads pf b128.
__device__ __forceinline__ void stage_kv32(const short* kbase, const short* vbase, int k0,
                                           short* KsB, short* VtB, int w, int lane) {
#pragma unroll
  for (int i = 0; i < 2; ++i) {
    int c = i * 4 + w;  // chunk-group of 64 chunks (64 lanes x 16B)
    int ch = c * 64 + lane;
    int r = ch >> 4, c8 = (ch & 15) * 8;                   // K: [32 rows][128 d]
    gload_lds16(kbase + (size_t)(k0 + r) * HDQ + (c8 ^ ((r & 7) << 3)), KsB + c * 512);
    int d = ch >> 2, k8 = (ch & 3) * 8;                    // V^T: [128 d][32 k]
    gload_lds16(vbase + (size_t)d * SQ + k0 + (k8 ^ (((d >> 1) & 3) << 3)), VtB + c * 512);
  }
}

__global__ __launch_bounds__(256, 4) void flash_kernel(const short* __restrict__ qb,
                                                       const short* __restrict__ kb,
                                                       const short* __restrict__ vtb,
                                                       short* __restrict__ ab) {
  __shared__ __align__(16) short Ks[2][32 * 128];
  __shared__ __align__(16) short Vt[2][128 * 32];
  __shared__ __align__(16) short Pl[4][16 * 32];
  int x = blockIdx.x, bh = blockIdx.y;
  int qt = (bh & 8) ? (31 - x) : x;
  int q0 = qt * 64;
  int tid = threadIdx.x, w = tid >> 6, lane = tid & 63;
  int g = lane >> 4, qcol = lane & 15;
  int qw0 = q0 + w * 16;
  const short* qbase = qb + (size_t)bh * SQ * HDQ;
  const short* kbase = kb + (size_t)bh * SQ * HDQ;
  const short* vbase = vtb + (size_t)bh * HDQ * SQ;
  int b = bh >> 4, h = bh & 15;

  bf16x8 qf[4];  // B-operand: col=q=qcol, k(d)= g*8+j (+cc*32)
#pragma unroll
  for (int cc = 0; cc < 4; ++cc)
    qf[cc] = *(const bf16x8*)&qbase[(size_t)(qw0 + qcol) * HDQ + cc * 32 + g * 8];

  f32x4 oacc[8] = {};
  float m_st = -1e30f, l_st = 0.f;
  int nt = 2 * qt + 2;
  stage_kv32(kbase, vbase, 0, Ks[0], Vt[0], w, lane);
#pragma unroll 1
  for (int t = 0; t < nt; ++t) {
    int cur = t & 1;
    int k0 = t * 32;
    __builtin_amdgcn_s_barrier();  // A: all waves done reading buf cur^1
    if (t + 1 < nt) {
      stage_kv32(kbase, vbase, (t + 1) * 32, Ks[cur ^ 1], Vt[cur ^ 1], w, lane);
      WAITVM4;  // current tile's 4 loads landed; next tile's 4 stay in flight
    } else {
      WAITVM0;
    }
    __builtin_amdgcn_s_barrier();  // B: all waves' current loads landed
    if (k0 > qw0 + 15) continue;   // fully-masked tile for this wave (barriers done)
    // ---- S^T = K * Q^T : C[k][q], lane: q=qcol fixed, k = nf*16 + g*4 + j ----
    f32x4 sacc[2] = {};
    __builtin_amdgcn_s_setprio(1);
#pragma unroll
    for (int nf = 0; nf < 2; ++nf) {
      int rk = nf * 16 + qcol;  // A-operand row = k index
#pragma unroll
      for (int cc = 0; cc < 4; ++cc) {
        int ck = cc * 32 + g * 8;
        bf16x8 kf = *(const bf16x8*)&Ks[cur][rk * 128 + (ck ^ ((rk & 7) << 3))];
        sacc[nf] = __builtin_amdgcn_mfma_f32_16x16x32_bf16(kf, qf[cc], sacc[nf], 0, 0, 0);
      }
    }
    __builtin_amdgcn_s_setprio(0);
    int q = qw0 + qcol;
    if (k0 + 31 > qw0) {  // diagonal region: mask k > q
#pragma unroll
      for (int nf = 0; nf < 2; ++nf)
#pragma unroll
        for (int j = 0; j < 4; ++j) {
          int k = k0 + nf * 16 + g * 4 + j;
          if (k > q) sacc[nf][j] = -1e9f;
        }
    }
    // ---- softmax (state scalar per lane; q = qcol) ----
    float mt = fmaxf(fmaxf(fmaxf(sacc[0][0], sacc[0][1]), fmaxf(sacc[0][2], sacc[0][3])),
                     fmaxf(fmaxf(sacc[1][0], sacc[1][1]), fmaxf(sacc[1][2], sacc[1][3])));
    mt = fmaxf(mt, __shfl_xor(mt, 16));
    mt = fmaxf(mt, __shfl_xor(mt, 32));
    float mn = fmaxf(m_st, mt);
    float al = exp2f(m_st - mn);
    float p0[4], p1[4];
    float ls = 0.f;
#pragma unroll
    for (int j = 0; j < 4; ++j) { p0[j] = exp2f(sacc[0][j] - mn); ls += p0[j]; }
#pragma unroll
    for (int j = 0; j < 4; ++j) { p1[j] = exp2f(sacc[1][j] - mn); ls += p1[j]; }
    l_st = l_st * al + ls;
    m_st = mn;
    // ---- P -> LDS (packed b64, swizzled) ----
    int sw = (qcol & 3) * 8;
    {
      bf16x4 pk;
      pk[0] = f2bf(p0[0]); pk[1] = f2bf(p0[1]); pk[2] = f2bf(p0[2]); pk[3] = f2bf(p0[3]);
      *(bf16x4*)&Pl[w][qcol * 32 + ((g * 4) ^ sw)] = pk;
      pk[0] = f2bf(p1[0]); pk[1] = f2bf(p1[1]); pk[2] = f2bf(p1[2]); pk[3] = f2bf(p1[3]);
      *(bf16x4*)&Pl[w][qcol * 32 + ((16 + g * 4) ^ sw)] = pk;
    }
    // ---- rescale oacc (broadcast al into oacc row layout) ----
    f32x4 alv;
    alv[0] = __shfl(al, g * 4 + 0);
    alv[1] = __shfl(al, g * 4 + 1);
    alv[2] = __shfl(al, g * 4 + 2);
    alv[3] = __shfl(al, g * 4 + 3);
#pragma unroll
    for (int df = 0; df < 8; ++df) oacc[df] *= alv;
    // ---- PV: A = P[q][k] (own row via LDS), B = V^T ----
    bf16x8 pf = *(const bf16x8*)&Pl[w][qcol * 32 + ((g * 8) ^ sw)];
    __builtin_amdgcn_s_setprio(1);
#pragma unroll
    for (int df = 0; df < 8; ++df) {
      int rd = df * 16 + qcol;
      bf16x8 vf = *(const bf16x8*)&Vt[cur][rd * 32 + ((g * 8) ^ (((rd >> 1) & 3) << 3))];
      oacc[df] = __builtin_amdgcn_mfma_f32_16x16x32_bf16(pf, vf, oacc[df], 0, 0, 0);
    }
    __builtin_amdgcn_s_setprio(0);
  }
  // ---- finalize ----
  l_st += __shfl_xor(l_st, 16);
  l_st += __shfl_xor(l_st, 32);
  float inv = 1.0f / l_st;
  f32x4 invv;
  invv[0] = __shfl(inv, g * 4 + 0);
  invv[1] = __shfl(inv, g * 4 + 1);
  invv[2] = __shfl(inv, g * 4 + 2);
  invv[3] = __shfl(inv, g * 4 + 3);
#pragma unroll
  for (int df = 0; df < 8; ++df)
#pragma unroll
    for (int j = 0; j < 4; ++j) {
      int qq = qw0 + g * 4 + j;
      int dd = df * 16 + qcol;
      ab[((size_t)b * SQ + qq) * DQ + h * HDQ + dd] = f2bf(oacc[df][j] * invv[j]);
    }
}

extern "C" void kernel_launch(void* const* d_in, const int* in_sizes, int n_in,
                              void* d_out, int out_size, void* d_ws, size_t ws_size,
                              hipStream_t stream) {
  (void)in_sizes; (void)n_in; (void)out_size; (void)ws_size;
  const float* x  = (const float*)d_in[0];
  const float* wq = (const float*)d_in[1];
  const float* wk = (const float*)d_in[2];
  const float* wv = (const float*)d_in[3];
  const float* wo = (const float*)d_in[4];
  const float* fc = (const float*)d_in[5];
  const float* fs = (const float*)d_in[6];
  // d_in[7] = mask (implemented analytically: causal, start_pos=0), d_in[8] = start_pos
  float* out = (float*)d_out;

  short* xb  = (short*)d_ws;              // 8,388,608 elems
  short* wqb = xb + (size_t)8388608;      // 4 weights, 4,194,304 each
  short* wkb = wqb + (size_t)4194304;
  short* wvb = wkb + (size_t)4194304;
  short* wob = wvb + (size_t)4194304;
  short* qb  = wob + (size_t)4194304;     // [B,H,S,HD] bf16
  short* kb  = qb + (size_t)8388608;
  short* ab  = kb + (size_t)8388608;      // attn out [B,S,D] bf16
  // V and V^T overlaid into d_out (33.5 MB, dead before final GEMM writes it)
  short* vb  = (short*)d_out;
  short* vtb = vb + (size_t)8388608;

  cvt_kernel<<<4096, 256, 0, stream>>>(x, xb, 1048576);
  cvt_kernel<<<2048, 256, 0, stream>>>(wq, wqb, 524288);
  cvt_kernel<<<2048, 256, 0, stream>>>(wk, wkb, 524288);
  cvt_kernel<<<2048, 256, 0, stream>>>(wv, wvb, 524288);
  cvt_kernel<<<2048, 256, 0, stream>>>(wo, wob, 524288);

  gemm_bt<0><<<dim3(16, 32, 3), 256, 0, stream>>>(xb, wqb, qb, kb, vb, nullptr);

  // Q scale = log2(e)/sqrt(HD) so flash softmax runs in exp2 domain
  rope_kernel<<<4096, 256, 0, stream>>>(qb, fc, fs, 0.12751744779976827f, 1048576);
  rope_kernel<<<4096, 256, 0, stream>>>(kb, fc, fs, 1.0f, 1048576);

  vtrans_kernel<<<dim3(2, 32, 32), 256, 0, stream>>>(vb, vtb);

  flash_kernel<<<dim3(32, 32), 256, 0, stream>>>(qb, kb, vtb, ab);

  gemm_bt<1><<<dim3(16, 32, 1), 256, 0, stream>>>(ab, wob, nullptr, nullptr, nullptr, out);
}